// Round 1
// baseline (5535.310 us; speedup 1.0000x reference)
//
#include <hip/hip_runtime.h>

// BasicIcoS2SUpBlock: upsample(2x nearest) -> [conv00->BN->ReLU] -> conv01->BN
//                                          \-> conv10->BN ; out = relu(bn01 + bn10)
// All fp32. Phase-decomposed convs on x directly (upsample collapsed).
//
// Shapes: x[16,64,160,64], w00[32,64,3,3], w01[32,32,3,3], w10[32,64,3,3],
// out [16,32,320,128]. Hex mask kills w[0][2], w[2][0].

#define CIN   64
#define COUT  32
#define HX    160
#define WX    64
#define HY    320
#define WY    128
#define NB    16
#define BN_EPS 1e-5f

// ---------------------------------------------------------------------------
// Weight prep: build phase-effective weights for convA (conv00, conv10) and
// masked tap list for convB (conv01).
// wA layout: [(conv*32+cout)*64+ci]*16 floats (14 used, 2 pad)
// wB layout: [(cout*32+ci)]*8 floats (7 used, 1 pad)
// ---------------------------------------------------------------------------
__global__ void prep_weights(const float* __restrict__ w00,
                             const float* __restrict__ w01,
                             const float* __restrict__ w10,
                             float* __restrict__ wA,
                             float* __restrict__ wB)
{
    int t = blockIdx.x * blockDim.x + threadIdx.x;
    if (t < 2 * COUT * CIN) {
        const float* src = (t < COUT * CIN) ? w00 : w10;
        int u = t % (COUT * CIN);
        const float* w = src + u * 9;
        float a = w[0], b = w[1], c = w[3], d = w[4], e5 = w[5], f = w[7], g = w[8];
        float* dst = wA + t * 16;
        // phase (0,0): xa,xb,xc,xd
        dst[0]  = a;
        dst[1]  = b;
        dst[2]  = c;
        dst[3]  = d + e5 + f + g;
        // phase (0,1): xb,xd,xe
        dst[4]  = a + b;
        dst[5]  = c + d + f;
        dst[6]  = e5 + g;
        // phase (1,0): xc,xd,xf
        dst[7]  = a + c;
        dst[8]  = b + d + e5;
        dst[9]  = f + g;
        // phase (1,1): xd,xe,xf,xg
        dst[10] = a + b + c + d;
        dst[11] = e5;
        dst[12] = f;
        dst[13] = g;
        dst[14] = 0.f;
        dst[15] = 0.f;
    } else if (t < 2 * COUT * CIN + COUT * COUT) {
        int u = t - 2 * COUT * CIN;
        const float* w = w01 + u * 9;
        float* dst = wB + u * 8;
        dst[0] = w[0]; dst[1] = w[1]; dst[2] = w[3]; dst[3] = w[4];
        dst[4] = w[5]; dst[5] = w[7]; dst[6] = w[8]; dst[7] = 0.f;
    }
}

// ---------------------------------------------------------------------------
// convA: conv00 + conv10 fused, phase-decomposed on x.
// Tile: 16x16 quads (=32x32 output px), 4 couts per block, 8 cout groups.
// LDS: 16ci x 18x18 halo tile of x. Rows wrap mod 160; cols zero-pad.
// Writes y0 (conv00 raw), y1 (conv10 raw), accumulates sum/sumsq per channel.
// statsA: [sum0[32], sq0[32], sum1[32], sq1[32]]
// ---------------------------------------------------------------------------
__global__ __launch_bounds__(256) void convA(
    const float* __restrict__ x, const float* __restrict__ wA,
    float* __restrict__ y0, float* __restrict__ y1,
    float* __restrict__ statsA)
{
    __shared__ float lds[16 * 324];
    const int tile  = blockIdx.x;      // 0..39 : 10 a-tiles x 4 b-tiles
    const int tb    = tile & 3;
    const int ta    = tile >> 2;
    const int batch = blockIdx.y;
    const int cout0 = blockIdx.z * 4;
    const int t     = threadIdx.x;
    const int qb    = t & 15;
    const int qa    = t >> 4;
    const int a     = ta * 16 + qa;
    const int b     = tb * 16 + qb;

    float acc[2][4][4];
#pragma unroll
    for (int cv = 0; cv < 2; ++cv)
#pragma unroll
        for (int g = 0; g < 4; ++g)
#pragma unroll
            for (int p = 0; p < 4; ++p) acc[cv][g][p] = 0.f;

    const int a0 = ta * 16 - 1;
    const int b0 = tb * 16 - 1;

    for (int chunk = 0; chunk < 4; ++chunk) {
        const int cbase = chunk * 16;
        __syncthreads();
        for (int k = t; k < 16 * 324; k += 256) {
            int ci = k / 324;
            int r  = k - ci * 324;
            int ra = r / 18, rb = r - ra * 18;
            int row = a0 + ra;
            row = (row + HX) % HX;           // wrap (a0 >= -1, row <= 160)
            int col = b0 + rb;
            float v = 0.f;
            if (col >= 0 && col < WX)
                v = x[((batch * CIN + cbase + ci) * HX + row) * WX + col];
            lds[k] = v;
        }
        __syncthreads();

        for (int ci = 0; ci < 16; ++ci) {
            const int off = ci * 324 + (qa + 1) * 18 + (qb + 1);
            const float xa = lds[off - 19], xb = lds[off - 18];
            const float xc = lds[off - 1],  xd = lds[off];
            const float xe = lds[off + 1],  xf = lds[off + 18];
            const float xg = lds[off + 19];
            const int cig = cbase + ci;
#pragma unroll
            for (int g = 0; g < 4; ++g) {
#pragma unroll
                for (int cv = 0; cv < 2; ++cv) {
                    const float* e = wA + ((cv * COUT + cout0 + g) * CIN + cig) * 16;
                    float s0 = acc[cv][g][0];
                    s0 = fmaf(e[0], xa, s0); s0 = fmaf(e[1], xb, s0);
                    s0 = fmaf(e[2], xc, s0); s0 = fmaf(e[3], xd, s0);
                    acc[cv][g][0] = s0;
                    float s1 = acc[cv][g][1];
                    s1 = fmaf(e[4], xb, s1); s1 = fmaf(e[5], xd, s1);
                    s1 = fmaf(e[6], xe, s1);
                    acc[cv][g][1] = s1;
                    float s2 = acc[cv][g][2];
                    s2 = fmaf(e[7], xc, s2); s2 = fmaf(e[8], xd, s2);
                    s2 = fmaf(e[9], xf, s2);
                    acc[cv][g][2] = s2;
                    float s3 = acc[cv][g][3];
                    s3 = fmaf(e[10], xd, s3); s3 = fmaf(e[11], xe, s3);
                    s3 = fmaf(e[12], xf, s3); s3 = fmaf(e[13], xg, s3);
                    acc[cv][g][3] = s3;
                }
            }
        }
    }

    // stores: each quad writes 2x2 output px as two float2
#pragma unroll
    for (int g = 0; g < 4; ++g) {
        const int cout = cout0 + g;
#pragma unroll
        for (int cv = 0; cv < 2; ++cv) {
            float* y = cv ? y1 : y0;
            const int base = (((batch * COUT + cout) * HY + 2 * a) * WY) + 2 * b;
            *(float2*)(y + base)      = make_float2(acc[cv][g][0], acc[cv][g][1]);
            *(float2*)(y + base + WY) = make_float2(acc[cv][g][2], acc[cv][g][3]);
        }
    }

    // stats: wave-reduce then one atomic per wave per counter
    const int lane = t & 63;
#pragma unroll
    for (int cv = 0; cv < 2; ++cv) {
#pragma unroll
        for (int g = 0; g < 4; ++g) {
            float s = acc[cv][g][0] + acc[cv][g][1] + acc[cv][g][2] + acc[cv][g][3];
            float q = acc[cv][g][0] * acc[cv][g][0] + acc[cv][g][1] * acc[cv][g][1]
                    + acc[cv][g][2] * acc[cv][g][2] + acc[cv][g][3] * acc[cv][g][3];
#pragma unroll
            for (int o = 32; o; o >>= 1) {
                s += __shfl_down(s, o);
                q += __shfl_down(q, o);
            }
            if (lane == 0) {
                atomicAdd(&statsA[cv * 64 + cout0 + g], s);
                atomicAdd(&statsA[cv * 64 + 32 + cout0 + g], q);
            }
        }
    }
}

// ---------------------------------------------------------------------------
// params_h: fold BN(stats of y0, g00, b00) into scale/shift for h staging.
// ph: [s[32], t[32]]
// ---------------------------------------------------------------------------
__global__ void params_h_kernel(const float* __restrict__ statsA,
                                const float* __restrict__ g00,
                                const float* __restrict__ b00,
                                float* __restrict__ ph)
{
    int c = threadIdx.x;
    if (c >= 32) return;
    const float n = (float)(NB * HY * WY);  // 655360
    float mean = statsA[c] / n;
    float var  = statsA[32 + c] / n - mean * mean;
    float rstd = rsqrtf(var + BN_EPS);
    float s = g00[c] * rstd;
    ph[c]      = s;
    ph[32 + c] = b00[c] - mean * s;
}

// ---------------------------------------------------------------------------
// convB: conv01 on h = relu(y0*s+t) computed while staging into LDS.
// Tile: 16x16 px, 8 couts per block, 4 cout groups. Rows wrap mod 320.
// stats2: [sum2[32], sq2[32]]
// ---------------------------------------------------------------------------
__global__ __launch_bounds__(256) void convB(
    const float* __restrict__ y0, const float* __restrict__ wB,
    const float* __restrict__ ph,
    float* __restrict__ y2, float* __restrict__ stats2)
{
    __shared__ float lds[16 * 324];
    __shared__ float sh_l[32], th_l[32];
    const int tile  = blockIdx.x;   // 0..159 : 20 i-tiles x 8 j-tiles
    const int tj    = tile & 7;
    const int ti    = tile >> 3;
    const int batch = blockIdx.y;
    const int cout0 = blockIdx.z * 8;
    const int t     = threadIdx.x;
    const int pj    = t & 15;
    const int pi    = t >> 4;
    const int i     = ti * 16 + pi;
    const int j     = tj * 16 + pj;

    if (t < 32) { sh_l[t] = ph[t]; th_l[t] = ph[32 + t]; }

    float acc[8];
#pragma unroll
    for (int g = 0; g < 8; ++g) acc[g] = 0.f;

    const int i0 = ti * 16 - 1;
    const int j0 = tj * 16 - 1;

    for (int chunk = 0; chunk < 2; ++chunk) {
        const int cbase = chunk * 16;
        __syncthreads();
        for (int k = t; k < 16 * 324; k += 256) {
            int ci = k / 324;
            int r  = k - ci * 324;
            int ra = r / 18, rb = r - ra * 18;
            int row = (i0 + ra + HY) % HY;
            int col = j0 + rb;
            float v = 0.f;
            int c = cbase + ci;
            if (col >= 0 && col < WY) {
                float u = y0[((batch * COUT + c) * HY + row) * WY + col];
                u = fmaf(u, sh_l[c], th_l[c]);
                v = u > 0.f ? u : 0.f;
            }
            lds[k] = v;
        }
        __syncthreads();

        for (int ci = 0; ci < 16; ++ci) {
            const int off = ci * 324 + (pi + 1) * 18 + (pj + 1);
            const float xa = lds[off - 19], xb = lds[off - 18];
            const float xc = lds[off - 1],  xd = lds[off];
            const float xe = lds[off + 1],  xf = lds[off + 18];
            const float xg = lds[off + 19];
            const int cig = cbase + ci;
#pragma unroll
            for (int g = 0; g < 8; ++g) {
                const float* w = wB + ((cout0 + g) * COUT + cig) * 8;
                float s = acc[g];
                s = fmaf(w[0], xa, s); s = fmaf(w[1], xb, s);
                s = fmaf(w[2], xc, s); s = fmaf(w[3], xd, s);
                s = fmaf(w[4], xe, s); s = fmaf(w[5], xf, s);
                s = fmaf(w[6], xg, s);
                acc[g] = s;
            }
        }
    }

#pragma unroll
    for (int g = 0; g < 8; ++g)
        y2[((batch * COUT + cout0 + g) * HY + i) * WY + j] = acc[g];

    const int lane = t & 63;
#pragma unroll
    for (int g = 0; g < 8; ++g) {
        float s = acc[g];
        float q = acc[g] * acc[g];
#pragma unroll
        for (int o = 32; o; o >>= 1) {
            s += __shfl_down(s, o);
            q += __shfl_down(q, o);
        }
        if (lane == 0) {
            atomicAdd(&stats2[cout0 + g], s);
            atomicAdd(&stats2[32 + cout0 + g], q);
        }
    }
}

// ---------------------------------------------------------------------------
// params_final: BN params for y1 (g10,b10) and y2 (g01,b01).
// pf: [s1[32], t1[32], s2[32], t2[32]]
// ---------------------------------------------------------------------------
__global__ void params_final_kernel(const float* __restrict__ statsA,
                                    const float* __restrict__ stats2,
                                    const float* __restrict__ g01,
                                    const float* __restrict__ b01,
                                    const float* __restrict__ g10,
                                    const float* __restrict__ b10,
                                    float* __restrict__ pf)
{
    int c = threadIdx.x;
    if (c >= 32) return;
    const float n = (float)(NB * HY * WY);
    float m1 = statsA[64 + c] / n;
    float v1 = statsA[96 + c] / n - m1 * m1;
    float r1 = rsqrtf(v1 + BN_EPS);
    float s1 = g10[c] * r1;
    pf[c]      = s1;
    pf[32 + c] = b10[c] - m1 * s1;
    float m2 = stats2[c] / n;
    float v2 = stats2[32 + c] / n - m2 * m2;
    float r2 = rsqrtf(v2 + BN_EPS);
    float s2 = g01[c] * r2;
    pf[64 + c] = s2;
    pf[96 + c] = b01[c] - m2 * s2;
}

// ---------------------------------------------------------------------------
// final: out = relu(bn(y2) + bn(y1)), float4 vectorized.
// ---------------------------------------------------------------------------
__global__ __launch_bounds__(256) void final_kernel(
    const float* __restrict__ y1, const float* __restrict__ y2,
    const float* __restrict__ pf, float* __restrict__ out)
{
    const int idx = blockIdx.x * 256 + threadIdx.x;   // float4 index, exact grid
    const int c = (idx / 10240) & 31;                 // 10240 float4 per (b,c) plane
    const float s1 = pf[c], t1 = pf[32 + c];
    const float s2 = pf[64 + c], t2 = pf[96 + c];
    const float4 a = ((const float4*)y2)[idx];
    const float4 d = ((const float4*)y1)[idx];
    float4 r;
    r.x = fmaf(a.x, s2, t2) + fmaf(d.x, s1, t1);
    r.y = fmaf(a.y, s2, t2) + fmaf(d.y, s1, t1);
    r.z = fmaf(a.z, s2, t2) + fmaf(d.z, s1, t1);
    r.w = fmaf(a.w, s2, t2) + fmaf(d.w, s1, t1);
    r.x = r.x > 0.f ? r.x : 0.f;
    r.y = r.y > 0.f ? r.y : 0.f;
    r.z = r.z > 0.f ? r.z : 0.f;
    r.w = r.w > 0.f ? r.w : 0.f;
    ((float4*)out)[idx] = r;
}

// ---------------------------------------------------------------------------
extern "C" void kernel_launch(void* const* d_in, const int* in_sizes, int n_in,
                              void* d_out, int out_size, void* d_ws, size_t ws_size,
                              hipStream_t stream)
{
    const float* x   = (const float*)d_in[0];
    const float* w00 = (const float*)d_in[1];
    const float* w01 = (const float*)d_in[2];
    const float* w10 = (const float*)d_in[3];
    const float* g00 = (const float*)d_in[4];
    const float* b00 = (const float*)d_in[5];
    const float* g01 = (const float*)d_in[6];
    const float* b01 = (const float*)d_in[7];
    const float* g10 = (const float*)d_in[8];
    const float* b10 = (const float*)d_in[9];
    float* out = (float*)d_out;

    // workspace layout (floats)
    float* ws     = (float*)d_ws;
    const int NPLANE = NB * COUT * HY * WY;       // 20,971,520
    float* y0     = ws;
    float* y1     = ws + (size_t)NPLANE;
    float* y2     = ws + (size_t)2 * NPLANE;
    float* statsA = ws + (size_t)3 * NPLANE;      // 128 floats
    float* stats2 = statsA + 128;                 // 64
    float* ph     = stats2 + 64;                  // 64
    float* pf     = ph + 64;                      // 128
    float* wA     = pf + 128;                     // 2*32*64*16 = 65536
    float* wB     = wA + 2 * COUT * CIN * 16;     // 32*32*8 = 8192

    hipMemsetAsync(statsA, 0, 192 * sizeof(float), stream);
    prep_weights<<<dim3(20), dim3(256), 0, stream>>>(w00, w01, w10, wA, wB);
    convA<<<dim3(40, 16, 8), dim3(256), 0, stream>>>(x, wA, y0, y1, statsA);
    params_h_kernel<<<dim3(1), dim3(32), 0, stream>>>(statsA, g00, b00, ph);
    convB<<<dim3(160, 16, 4), dim3(256), 0, stream>>>(y0, wB, ph, y2, stats2);
    params_final_kernel<<<dim3(1), dim3(32), 0, stream>>>(statsA, stats2, g01, b01, g10, b10, pf);
    final_kernel<<<dim3(NPLANE / 4 / 256), dim3(256), 0, stream>>>(y1, y2, pf, out);
}

// Round 2
// 943.593 us; speedup vs baseline: 5.8662x; 5.8662x over previous
//
#include <hip/hip_runtime.h>

// BasicIcoS2SUpBlock: upsample(2x nearest) -> [conv00->BN->ReLU] -> conv01->BN
//                                          \-> conv10->BN ; out = relu(bn01 + bn10)
// All fp32. Phase-decomposed convs on x directly (upsample collapsed).
// R2: stats atomics removed from conv kernels (R1: 655K same-address atomics
//     serialized convB to 4.1ms @ 4.3% VALUBusy). Dedicated stats pass instead.
//     convB: all 32 couts/block; convA: 8 couts/block.

#define CIN   64
#define COUT  32
#define HX    160
#define WX    64
#define HY    320
#define WY    128
#define NB    16
#define BN_EPS 1e-5f

// ---------------------------------------------------------------------------
// Weight prep: phase-effective weights for convA (conv00, conv10), masked tap
// list for convB (conv01).
// wA: [(conv*32+cout)*64+ci]*16 floats (14 used). wB: [cout*32+ci]*8 (7 used).
// ---------------------------------------------------------------------------
__global__ void prep_weights(const float* __restrict__ w00,
                             const float* __restrict__ w01,
                             const float* __restrict__ w10,
                             float* __restrict__ wA,
                             float* __restrict__ wB)
{
    int t = blockIdx.x * blockDim.x + threadIdx.x;
    if (t < 2 * COUT * CIN) {
        const float* src = (t < COUT * CIN) ? w00 : w10;
        int u = t % (COUT * CIN);
        const float* w = src + u * 9;
        float a = w[0], b = w[1], c = w[3], d = w[4], e5 = w[5], f = w[7], g = w[8];
        float* dst = wA + t * 16;
        dst[0]  = a;            // phase (0,0): xa,xb,xc,xd
        dst[1]  = b;
        dst[2]  = c;
        dst[3]  = d + e5 + f + g;
        dst[4]  = a + b;        // phase (0,1): xb,xd,xe
        dst[5]  = c + d + f;
        dst[6]  = e5 + g;
        dst[7]  = a + c;        // phase (1,0): xc,xd,xf
        dst[8]  = b + d + e5;
        dst[9]  = f + g;
        dst[10] = a + b + c + d;// phase (1,1): xd,xe,xf,xg
        dst[11] = e5;
        dst[12] = f;
        dst[13] = g;
        dst[14] = 0.f;
        dst[15] = 0.f;
    } else if (t < 2 * COUT * CIN + COUT * COUT) {
        int u = t - 2 * COUT * CIN;
        const float* w = w01 + u * 9;
        float* dst = wB + u * 8;
        dst[0] = w[0]; dst[1] = w[1]; dst[2] = w[3]; dst[3] = w[4];
        dst[4] = w[5]; dst[5] = w[7]; dst[6] = w[8]; dst[7] = 0.f;
    }
}

// ---------------------------------------------------------------------------
// convA: conv00 + conv10 fused, phase-decomposed on x. No stats.
// Tile: 16x16 quads (=32x32 out px), 8 couts/block (z=4).
// LDS: 16ci x 18x18 halo of x. Rows wrap mod 160; cols zero-pad.
// ---------------------------------------------------------------------------
__global__ __launch_bounds__(256) void convA(
    const float* __restrict__ x, const float* __restrict__ wA,
    float* __restrict__ y0, float* __restrict__ y1)
{
    __shared__ float lds[16 * 324];
    const int tile  = blockIdx.x;      // 0..39 : 10 a-tiles x 4 b-tiles
    const int tb    = tile & 3;
    const int ta    = tile >> 2;
    const int batch = blockIdx.y;
    const int cout0 = blockIdx.z * 8;
    const int t     = threadIdx.x;
    const int qb    = t & 15;
    const int qa    = t >> 4;
    const int a     = ta * 16 + qa;
    const int b     = tb * 16 + qb;

    float acc[2][8][4];
#pragma unroll
    for (int cv = 0; cv < 2; ++cv)
#pragma unroll
        for (int g = 0; g < 8; ++g)
#pragma unroll
            for (int p = 0; p < 4; ++p) acc[cv][g][p] = 0.f;

    const int a0 = ta * 16 - 1;
    const int b0 = tb * 16 - 1;

    for (int chunk = 0; chunk < 4; ++chunk) {
        const int cbase = chunk * 16;
        __syncthreads();
        for (int k = t; k < 16 * 324; k += 256) {
            int ci = k / 324;
            int r  = k - ci * 324;
            int ra = r / 18, rb = r - ra * 18;
            int row = (a0 + ra + HX) % HX;     // wrap
            int col = b0 + rb;
            float v = 0.f;
            if (col >= 0 && col < WX)
                v = x[((batch * CIN + cbase + ci) * HX + row) * WX + col];
            lds[k] = v;
        }
        __syncthreads();

        for (int ci = 0; ci < 16; ++ci) {
            const int off = ci * 324 + (qa + 1) * 18 + (qb + 1);
            const float xa = lds[off - 19], xb = lds[off - 18];
            const float xc = lds[off - 1],  xd = lds[off];
            const float xe = lds[off + 1],  xf = lds[off + 18];
            const float xg = lds[off + 19];
            const int cig = cbase + ci;
#pragma unroll
            for (int g = 0; g < 8; ++g) {
#pragma unroll
                for (int cv = 0; cv < 2; ++cv) {
                    const float* e = wA + ((cv * COUT + cout0 + g) * CIN + cig) * 16;
                    float s0 = acc[cv][g][0];
                    s0 = fmaf(e[0], xa, s0); s0 = fmaf(e[1], xb, s0);
                    s0 = fmaf(e[2], xc, s0); s0 = fmaf(e[3], xd, s0);
                    acc[cv][g][0] = s0;
                    float s1 = acc[cv][g][1];
                    s1 = fmaf(e[4], xb, s1); s1 = fmaf(e[5], xd, s1);
                    s1 = fmaf(e[6], xe, s1);
                    acc[cv][g][1] = s1;
                    float s2 = acc[cv][g][2];
                    s2 = fmaf(e[7], xc, s2); s2 = fmaf(e[8], xd, s2);
                    s2 = fmaf(e[9], xf, s2);
                    acc[cv][g][2] = s2;
                    float s3 = acc[cv][g][3];
                    s3 = fmaf(e[10], xd, s3); s3 = fmaf(e[11], xe, s3);
                    s3 = fmaf(e[12], xf, s3); s3 = fmaf(e[13], xg, s3);
                    acc[cv][g][3] = s3;
                }
            }
        }
    }

#pragma unroll
    for (int g = 0; g < 8; ++g) {
        const int cout = cout0 + g;
#pragma unroll
        for (int cv = 0; cv < 2; ++cv) {
            float* y = cv ? y1 : y0;
            const int base = (((batch * COUT + cout) * HY + 2 * a) * WY) + 2 * b;
            *(float2*)(y + base)      = make_float2(acc[cv][g][0], acc[cv][g][1]);
            *(float2*)(y + base + WY) = make_float2(acc[cv][g][2], acc[cv][g][3]);
        }
    }
}

// ---------------------------------------------------------------------------
// stats: per-channel sum/sumsq of y [NB,32,HY,WY]. One block per (b,c) plane,
// float4 reads, LDS reduce, 2 atomics/block (16 per address total).
// out: [sum[32], sq[32]]
// ---------------------------------------------------------------------------
__global__ __launch_bounds__(256) void stats_kernel(
    const float* __restrict__ y, float* __restrict__ out)
{
    const int plane = blockIdx.x;          // b*32+c
    const int c = plane & 31;
    const float4* p = (const float4*)(y + (size_t)plane * (HY * WY));
    float s = 0.f, q = 0.f;
    for (int k = threadIdx.x; k < HY * WY / 4; k += 256) {
        float4 v = p[k];
        s += v.x + v.y + v.z + v.w;
        q += v.x * v.x + v.y * v.y + v.z * v.z + v.w * v.w;
    }
#pragma unroll
    for (int o = 32; o; o >>= 1) {
        s += __shfl_down(s, o);
        q += __shfl_down(q, o);
    }
    __shared__ float ss[4], qq[4];
    const int lane = threadIdx.x & 63, w = threadIdx.x >> 6;
    if (lane == 0) { ss[w] = s; qq[w] = q; }
    __syncthreads();
    if (threadIdx.x == 0) {
        s = ss[0] + ss[1] + ss[2] + ss[3];
        q = qq[0] + qq[1] + qq[2] + qq[3];
        atomicAdd(&out[c], s);
        atomicAdd(&out[32 + c], q);
    }
}

// ---------------------------------------------------------------------------
// params_h: fold BN(stats of y0, g00, b00) into scale/shift. ph: [s[32],t[32]]
// ---------------------------------------------------------------------------
__global__ void params_h_kernel(const float* __restrict__ statsA,
                                const float* __restrict__ g00,
                                const float* __restrict__ b00,
                                float* __restrict__ ph)
{
    int c = threadIdx.x;
    if (c >= 32) return;
    const float n = (float)(NB * HY * WY);
    float mean = statsA[c] / n;
    float var  = statsA[32 + c] / n - mean * mean;
    float rstd = rsqrtf(var + BN_EPS);
    float s = g00[c] * rstd;
    ph[c]      = s;
    ph[32 + c] = b00[c] - mean * s;
}

// ---------------------------------------------------------------------------
// convB: conv01 on h = relu(y0*s+t), BN+ReLU fused into LDS staging.
// Tile: 16x16 px, ALL 32 couts per block. Rows wrap mod 320. No stats.
// ---------------------------------------------------------------------------
__global__ __launch_bounds__(256) void convB(
    const float* __restrict__ y0, const float* __restrict__ wB,
    const float* __restrict__ ph, float* __restrict__ y2)
{
    __shared__ float lds[16 * 324];
    __shared__ float sh_l[32], th_l[32];
    const int tile  = blockIdx.x;   // 0..159 : 20 i-tiles x 8 j-tiles
    const int tj    = tile & 7;
    const int ti    = tile >> 3;
    const int batch = blockIdx.y;
    const int t     = threadIdx.x;
    const int pj    = t & 15;
    const int pi    = t >> 4;
    const int i     = ti * 16 + pi;
    const int j     = tj * 16 + pj;

    if (t < 32) { sh_l[t] = ph[t]; th_l[t] = ph[32 + t]; }

    float acc[32];
#pragma unroll
    for (int g = 0; g < 32; ++g) acc[g] = 0.f;

    const int i0 = ti * 16 - 1;
    const int j0 = tj * 16 - 1;

    for (int chunk = 0; chunk < 2; ++chunk) {
        const int cbase = chunk * 16;
        __syncthreads();
        for (int k = t; k < 16 * 324; k += 256) {
            int ci = k / 324;
            int r  = k - ci * 324;
            int ra = r / 18, rb = r - ra * 18;
            int row = (i0 + ra + HY) % HY;
            int col = j0 + rb;
            float v = 0.f;
            int c = cbase + ci;
            if (col >= 0 && col < WY) {
                float u = y0[((batch * COUT + c) * HY + row) * WY + col];
                u = fmaf(u, sh_l[c], th_l[c]);
                v = u > 0.f ? u : 0.f;
            }
            lds[k] = v;
        }
        __syncthreads();

        for (int ci = 0; ci < 16; ++ci) {
            const int off = ci * 324 + (pi + 1) * 18 + (pj + 1);
            const float xa = lds[off - 19], xb = lds[off - 18];
            const float xc = lds[off - 1],  xd = lds[off];
            const float xe = lds[off + 1],  xf = lds[off + 18];
            const float xg = lds[off + 19];
            const int cig = cbase + ci;
#pragma unroll
            for (int g = 0; g < 32; ++g) {
                const float* w = wB + (g * COUT + cig) * 8;
                float s = acc[g];
                s = fmaf(w[0], xa, s); s = fmaf(w[1], xb, s);
                s = fmaf(w[2], xc, s); s = fmaf(w[3], xd, s);
                s = fmaf(w[4], xe, s); s = fmaf(w[5], xf, s);
                s = fmaf(w[6], xg, s);
                acc[g] = s;
            }
        }
    }

#pragma unroll
    for (int g = 0; g < 32; ++g)
        y2[((batch * COUT + g) * HY + i) * WY + j] = acc[g];
}

// ---------------------------------------------------------------------------
// params_final: BN params for y1 (g10,b10) and y2 (g01,b01).
// pf: [s1[32], t1[32], s2[32], t2[32]]
// ---------------------------------------------------------------------------
__global__ void params_final_kernel(const float* __restrict__ statsA,
                                    const float* __restrict__ stats2,
                                    const float* __restrict__ g01,
                                    const float* __restrict__ b01,
                                    const float* __restrict__ g10,
                                    const float* __restrict__ b10,
                                    float* __restrict__ pf)
{
    int c = threadIdx.x;
    if (c >= 32) return;
    const float n = (float)(NB * HY * WY);
    float m1 = statsA[64 + c] / n;
    float v1 = statsA[96 + c] / n - m1 * m1;
    float r1 = rsqrtf(v1 + BN_EPS);
    float s1 = g10[c] * r1;
    pf[c]      = s1;
    pf[32 + c] = b10[c] - m1 * s1;
    float m2 = stats2[c] / n;
    float v2 = stats2[32 + c] / n - m2 * m2;
    float r2 = rsqrtf(v2 + BN_EPS);
    float s2 = g01[c] * r2;
    pf[64 + c] = s2;
    pf[96 + c] = b01[c] - m2 * s2;
}

// ---------------------------------------------------------------------------
// final: out = relu(bn(y2) + bn(y1)), float4 vectorized.
// ---------------------------------------------------------------------------
__global__ __launch_bounds__(256) void final_kernel(
    const float* __restrict__ y1, const float* __restrict__ y2,
    const float* __restrict__ pf, float* __restrict__ out)
{
    const int idx = blockIdx.x * 256 + threadIdx.x;   // float4 index, exact grid
    const int c = (idx / 10240) & 31;                 // 10240 float4 per (b,c) plane
    const float s1 = pf[c], t1 = pf[32 + c];
    const float s2 = pf[64 + c], t2 = pf[96 + c];
    const float4 a = ((const float4*)y2)[idx];
    const float4 d = ((const float4*)y1)[idx];
    float4 r;
    r.x = fmaf(a.x, s2, t2) + fmaf(d.x, s1, t1);
    r.y = fmaf(a.y, s2, t2) + fmaf(d.y, s1, t1);
    r.z = fmaf(a.z, s2, t2) + fmaf(d.z, s1, t1);
    r.w = fmaf(a.w, s2, t2) + fmaf(d.w, s1, t1);
    r.x = r.x > 0.f ? r.x : 0.f;
    r.y = r.y > 0.f ? r.y : 0.f;
    r.z = r.z > 0.f ? r.z : 0.f;
    r.w = r.w > 0.f ? r.w : 0.f;
    ((float4*)out)[idx] = r;
}

// ---------------------------------------------------------------------------
extern "C" void kernel_launch(void* const* d_in, const int* in_sizes, int n_in,
                              void* d_out, int out_size, void* d_ws, size_t ws_size,
                              hipStream_t stream)
{
    const float* x   = (const float*)d_in[0];
    const float* w00 = (const float*)d_in[1];
    const float* w01 = (const float*)d_in[2];
    const float* w10 = (const float*)d_in[3];
    const float* g00 = (const float*)d_in[4];
    const float* b00 = (const float*)d_in[5];
    const float* g01 = (const float*)d_in[6];
    const float* b01 = (const float*)d_in[7];
    const float* g10 = (const float*)d_in[8];
    const float* b10 = (const float*)d_in[9];
    float* out = (float*)d_out;

    float* ws     = (float*)d_ws;
    const int NPLANE = NB * COUT * HY * WY;       // 20,971,520
    float* y0     = ws;
    float* y1     = ws + (size_t)NPLANE;
    float* y2     = ws + (size_t)2 * NPLANE;
    float* statsA = ws + (size_t)3 * NPLANE;      // 128 floats
    float* stats2 = statsA + 128;                 // 64
    float* ph     = stats2 + 64;                  // 64
    float* pf     = ph + 64;                      // 128
    float* wA     = pf + 128;                     // 2*32*64*16 = 65536
    float* wB     = wA + 2 * COUT * CIN * 16;     // 32*32*8 = 8192

    hipMemsetAsync(statsA, 0, 192 * sizeof(float), stream);
    prep_weights<<<dim3(20), dim3(256), 0, stream>>>(w00, w01, w10, wA, wB);
    convA<<<dim3(40, 16, 4), dim3(256), 0, stream>>>(x, wA, y0, y1);
    stats_kernel<<<dim3(NB * COUT), dim3(256), 0, stream>>>(y0, statsA);
    stats_kernel<<<dim3(NB * COUT), dim3(256), 0, stream>>>(y1, statsA + 64);
    params_h_kernel<<<dim3(1), dim3(32), 0, stream>>>(statsA, g00, b00, ph);
    convB<<<dim3(160, 16), dim3(256), 0, stream>>>(y0, wB, ph, y2);
    stats_kernel<<<dim3(NB * COUT), dim3(256), 0, stream>>>(y2, stats2);
    params_final_kernel<<<dim3(1), dim3(32), 0, stream>>>(statsA, stats2, g01, b01, g10, b10, pf);
    final_kernel<<<dim3(NPLANE / 4 / 256), dim3(256), 0, stream>>>(y1, y2, pf, out);
}

// Round 3
// 424.769 us; speedup vs baseline: 13.0313x; 2.2214x over previous
//
#include <hip/hip_runtime.h>
#include <hip/hip_bf16.h>

// BasicIcoS2SUpBlock — R3: bf16 MFMA implicit-GEMM version.
// upsample collapsed via phase decomposition; conv = sum of shifted GEMMs
// (K = cin) using mfma_f32_16x16x32_bf16. Stats fused as per-block partials
// (no same-address atomics — R1 lesson). y0 staged NHWC bf16 for convB.

#define CIN   64
#define COUT  32
#define HX    160
#define WX    64
#define HY    320
#define WY    128
#define NB    16
#define BN_EPS 1e-5f

typedef short s16x8 __attribute__((ext_vector_type(8)));
typedef float f32x4 __attribute__((ext_vector_type(4)));

// ---------------------------------------------------------------------------
// prep_x: x NCHW fp32 -> xt NHWC bf16 ([n][row160][col64][ci64], ci contig)
// ---------------------------------------------------------------------------
__global__ __launch_bounds__(256) void prep_x(const float* __restrict__ x,
                                              __hip_bfloat16* __restrict__ xt)
{
    __shared__ float tile[64][65];
    const int n  = blockIdx.y;
    const int p0 = blockIdx.x * 64;        // pixel tile (row-major px in-plane)
    const int t  = threadIdx.x;
#pragma unroll
    for (int e = 0; e < 16; ++e) {
        int k = e * 256 + t;
        int ci = k >> 6, p = k & 63;
        tile[ci][p] = x[(n * CIN + ci) * (HX * WX) + p0 + p];
    }
    __syncthreads();
#pragma unroll
    for (int e = 0; e < 16; ++e) {
        int k = e * 256 + t;
        int p = k >> 6, ci = k & 63;
        xt[((size_t)n * (HX * WX) + p0 + p) * 64 + ci] = __float2bfloat16(tile[ci][p]);
    }
}

// ---------------------------------------------------------------------------
// prep_w: effective phase weights (bf16).
// wAb: [cv(2)][slot(16)][co(32)][ci(64)]  slots = ph*4+s, dummy slots 7,11 = 0
// wBb: [tap(7)][co(32)][ci(32)]
// ---------------------------------------------------------------------------
__global__ __launch_bounds__(256) void prep_w(const float* __restrict__ w00,
                                              const float* __restrict__ w01,
                                              const float* __restrict__ w10,
                                              __hip_bfloat16* __restrict__ wAb,
                                              __hip_bfloat16* __restrict__ wBb)
{
    int t = blockIdx.x * 256 + threadIdx.x;
    if (t < 4096) {                       // convA weights
        int cv = t >> 11, u = t & 2047;
        int co = u >> 6, ci = u & 63;
        const float* w = (cv ? w10 : w00) + (co * 64 + ci) * 9;
        float a = w[0], b = w[1], c = w[3], d = w[4], e5 = w[5], f = w[7], g = w[8];
        float v[16];
        v[0] = a;             v[1] = b;           v[2] = c;       v[3] = d + e5 + f + g;
        v[4] = a + b;         v[5] = c + d + f;   v[6] = e5 + g;  v[7] = 0.f;
        v[8] = a + c;         v[9] = b + d + e5;  v[10] = f + g;  v[11] = 0.f;
        v[12] = a + b + c + d; v[13] = e5;        v[14] = f;      v[15] = g;
#pragma unroll
        for (int s = 0; s < 16; ++s)
            wAb[(((size_t)cv * 16 + s) * 32 + co) * 64 + ci] = __float2bfloat16(v[s]);
    } else if (t < 5120) {                // convB weights (hex taps of 3x3)
        int u = t - 4096;
        int co = u >> 5, ci = u & 31;
        const float* w = w01 + (co * 32 + ci) * 9;
        const int wi[7] = {0, 1, 3, 4, 5, 7, 8};
#pragma unroll
        for (int s = 0; s < 7; ++s)
            wBb[((size_t)s * 32 + co) * 32 + ci] = __float2bfloat16(w[wi[s]]);
    }
}

// ---------------------------------------------------------------------------
// convA: conv00 (cv=0 -> y0 NHWC bf16) / conv10 (cv=1 -> y1 NCHW fp32),
// phase-decomposed, MFMA 16x16x32 bf16. Block: 16x16 x-tile, 4 waves x 4 rows.
// LDS x-tile [18][18][ci 64 pad 72] bf16. Partial stats -> partialsA[cv][blk][64].
// ---------------------------------------------------------------------------
__global__ __launch_bounds__(256) void convA(
    const __hip_bfloat16* __restrict__ xt, const __hip_bfloat16* __restrict__ wAb,
    __hip_bfloat16* __restrict__ y0h, float* __restrict__ y1,
    float* __restrict__ partialsA)
{
    __shared__ short lds[324 * 72];            // 18*18 chunks x 72 bf16 = 46656 B
    const int tb = blockIdx.x & 3, ta = blockIdx.x >> 2;
    const int nb = blockIdx.y, cv = blockIdx.z;
    const int t = threadIdx.x, wave = t >> 6, lane = t & 63;
    const int n = lane & 15, q = lane >> 4;
    const int a0 = ta * 16, b0 = tb * 16;

    // ---- stage x tile (rows wrap mod 160, cols zero-pad) ----
    for (int idx = t; idx < 2592; idx += 256) {       // 324 chunks * 8 lanes
        int chunk = idx >> 3, sub = idx & 7;
        int rl = chunk / 18, cl = chunk - rl * 18;
        int grow = a0 - 1 + rl;
        if (grow < 0) grow += HX; else if (grow >= HX) grow -= HX;
        int gcol = b0 - 1 + cl;
        uint4 v = make_uint4(0u, 0u, 0u, 0u);
        if ((unsigned)gcol < (unsigned)WX)
            v = *(const uint4*)(xt + (((size_t)nb * HX + grow) * WX + gcol) * 64 + sub * 8);
        *(uint4*)(&lds[chunk * 72 + sub * 8]) = v;
    }
    __syncthreads();

    // tap shifts per slot (ph*4+s); dummy slots point at (0,0), weight = 0
    const int dr16[16] = {-1,-1, 0, 0,  -1, 0, 0, 0,   0, 0, 1, 0,   0, 0, 1, 1};
    const int dc16[16] = {-1, 0,-1, 0,   0, 0, 1, 0,  -1, 0, 0, 0,   0, 1, 0, 1};

    float st[2][4], sq2[2][4];
#pragma unroll
    for (int h = 0; h < 2; ++h)
#pragma unroll
        for (int r = 0; r < 4; ++r) { st[h][r] = 0.f; sq2[h][r] = 0.f; }

#pragma unroll
    for (int ph = 0; ph < 4; ++ph) {
        const int pa = ph >> 1, pb = ph & 1;
        // A fragments: [tap][kc][h]
        s16x8 A[4][2][2];
#pragma unroll
        for (int ti = 0; ti < 4; ++ti)
#pragma unroll
            for (int kc = 0; kc < 2; ++kc)
#pragma unroll
                for (int h = 0; h < 2; ++h)
                    A[ti][kc][h] = *(const s16x8*)(wAb +
                        (((size_t)cv * 16 + ph * 4 + ti) * 32 + h * 16 + n) * 64 + kc * 32 + q * 8);
#pragma unroll
        for (int rr = 0; rr < 4; ++rr) {
            const int rl = wave * 4 + rr;
            s16x8 B[4][2];
#pragma unroll
            for (int ti = 0; ti < 4; ++ti) {
                const int off = ((rl + 1 + dr16[ph * 4 + ti]) * 18 + (n + 1 + dc16[ph * 4 + ti])) * 72;
#pragma unroll
                for (int kc = 0; kc < 2; ++kc)
                    B[ti][kc] = *(const s16x8*)(&lds[off + kc * 32 + q * 8]);
            }
            f32x4 acc[2];
            acc[0] = (f32x4){0.f, 0.f, 0.f, 0.f};
            acc[1] = (f32x4){0.f, 0.f, 0.f, 0.f};
#pragma unroll
            for (int ti = 0; ti < 4; ++ti)
#pragma unroll
                for (int kc = 0; kc < 2; ++kc)
#pragma unroll
                    for (int h = 0; h < 2; ++h)
                        acc[h] = __builtin_amdgcn_mfma_f32_16x16x32_bf16(
                            A[ti][kc][h], B[ti][kc], acc[h], 0, 0, 0);
            // store: out pixel (i, j), co = h*16 + q*4 + reg
            const int i = 2 * (a0 + rl) + pa;
            const int j = 2 * b0 + pb + 2 * n;
            if (cv == 0) {
                __hip_bfloat16* p = y0h + (((size_t)nb * HY + i) * WY + j) * 32;
#pragma unroll
                for (int h = 0; h < 2; ++h) {
                    __hip_bfloat162 lo = __float22bfloat162_rn(make_float2(acc[h][0], acc[h][1]));
                    __hip_bfloat162 hi = __float22bfloat162_rn(make_float2(acc[h][2], acc[h][3]));
                    __hip_bfloat162* pp = (__hip_bfloat162*)(p + h * 16 + q * 4);
                    pp[0] = lo; pp[1] = hi;
                }
            } else {
#pragma unroll
                for (int h = 0; h < 2; ++h)
#pragma unroll
                    for (int r = 0; r < 4; ++r) {
                        const int co = h * 16 + q * 4 + r;
                        y1[(((size_t)nb * 32 + co) * HY + i) * WY + j] = acc[h][r];
                    }
            }
#pragma unroll
            for (int h = 0; h < 2; ++h)
#pragma unroll
                for (int r = 0; r < 4; ++r) {
                    float v = acc[h][r];
                    st[h][r] += v; sq2[h][r] += v * v;
                }
        }
    }

    // ---- per-block stats reduction ----
    __syncthreads();
    float* scratch = (float*)lds;              // [wave][co][2]
#pragma unroll
    for (int h = 0; h < 2; ++h)
#pragma unroll
        for (int r = 0; r < 4; ++r) {
            float s = st[h][r], qv = sq2[h][r];
#pragma unroll
            for (int m = 1; m < 16; m <<= 1) {
                s  += __shfl_xor(s, m, 16);
                qv += __shfl_xor(qv, m, 16);
            }
            if (n == 0) {
                const int co = h * 16 + q * 4 + r;
                scratch[(wave * 32 + co) * 2]     = s;
                scratch[(wave * 32 + co) * 2 + 1] = qv;
            }
        }
    __syncthreads();
    if (t < 64) {
        const int co = t & 31, which = t >> 5;
        float s = scratch[(0 * 32 + co) * 2 + which] + scratch[(1 * 32 + co) * 2 + which]
                + scratch[(2 * 32 + co) * 2 + which] + scratch[(3 * 32 + co) * 2 + which];
        const int blk = blockIdx.y * 40 + blockIdx.x;          // 0..639
        partialsA[((size_t)cv * 640 + blk) * 64 + which * 32 + co] = s;
    }
}

// ---------------------------------------------------------------------------
// params_h: reduce partialsA (cv=0) -> BN scale/shift for h. phs: [s32, t32]
// ---------------------------------------------------------------------------
__global__ __launch_bounds__(256) void params_h_kernel(
    const float* __restrict__ partialsA, const float* __restrict__ g00,
    const float* __restrict__ b00, float* __restrict__ phs)
{
    __shared__ float red[4][64];
    __shared__ float tot[64];
    const int t = threadIdx.x, c = t & 63, seg = t >> 6;
    float s = 0.f;
    for (int b = seg; b < 640; b += 4) s += partialsA[(size_t)b * 64 + c];
    red[seg][c] = s;
    __syncthreads();
    if (t < 64) tot[t] = red[0][t] + red[1][t] + red[2][t] + red[3][t];
    __syncthreads();
    if (t < 32) {
        const float nf = (float)(NB * HY * WY);
        float mean = tot[t] / nf;
        float var  = tot[32 + t] / nf - mean * mean;
        float sc = g00[t] * rsqrtf(var + BN_EPS);
        phs[t] = sc;
        phs[32 + t] = b00[t] - mean * sc;
    }
}

// ---------------------------------------------------------------------------
// convB: conv01 on h = relu(bn(y0)) (BN+ReLU fused into bf16 staging).
// Block: 16x32 out-tile, LDS [18][34][ci 32 pad 40]. MFMA 16x16x32, K=32.
// ---------------------------------------------------------------------------
__global__ __launch_bounds__(256) void convB(
    const __hip_bfloat16* __restrict__ y0h, const __hip_bfloat16* __restrict__ wBb,
    const float* __restrict__ phs, float* __restrict__ y2,
    float* __restrict__ partialsB)
{
    __shared__ short lds[612 * 40];            // 18*34 chunks x 40 = 48960 B
    const int tj = blockIdx.x & 3, ti = blockIdx.x >> 2;
    const int nb = blockIdx.y;
    const int t = threadIdx.x, wave = t >> 6, lane = t & 63;
    const int n = lane & 15, q = lane >> 4;
    const int i0 = ti * 16, j0 = tj * 32;

    // BN params for this lane's 8 staged channels
    const int cis = (t & 3) * 8;
    float sv[8], tv[8];
#pragma unroll
    for (int e = 0; e < 8; ++e) { sv[e] = phs[cis + e]; tv[e] = phs[32 + cis + e]; }

    // ---- stage h tile ----
    for (int idx = t; idx < 2448; idx += 256) {      // 612 chunks * 4 lanes
        int chunk = idx >> 2, sub = idx & 3;         // sub == t&3 (256 % 4 == 0)
        int rl = chunk / 34, cl = chunk - rl * 34;
        int grow = i0 - 1 + rl;
        if (grow < 0) grow += HY; else if (grow >= HY) grow -= HY;
        int gcol = j0 - 1 + cl;
        uint4 w = make_uint4(0u, 0u, 0u, 0u);
        if ((unsigned)gcol < (unsigned)WY) {
            uint4 v = *(const uint4*)(y0h + (((size_t)nb * HY + grow) * WY + gcol) * 32 + sub * 8);
            unsigned* vi = (unsigned*)&v;
            unsigned* wi = (unsigned*)&w;
#pragma unroll
            for (int k = 0; k < 4; ++k) {
                unsigned u = vi[k];
                float f0 = __uint_as_float(u << 16);
                float f1 = __uint_as_float(u & 0xffff0000u);
                f0 = fmaxf(fmaf(f0, sv[2 * k], tv[2 * k]), 0.f);
                f1 = fmaxf(fmaf(f1, sv[2 * k + 1], tv[2 * k + 1]), 0.f);
                union { __hip_bfloat162 b2; unsigned u32; } cvt;
                cvt.b2 = __float22bfloat162_rn(make_float2(f0, f1));
                wi[k] = cvt.u32;
            }
        }
        *(uint4*)(&lds[chunk * 40 + sub * 8]) = w;
    }
    __syncthreads();

    // A fragments [tap][h]
    s16x8 A[7][2];
#pragma unroll
    for (int s = 0; s < 7; ++s)
#pragma unroll
        for (int h = 0; h < 2; ++h)
            A[s][h] = *(const s16x8*)(wBb + ((size_t)s * 32 + h * 16 + n) * 32 + q * 8);

    const int dr7[7] = {-1, -1, 0, 0, 0, 1, 1};
    const int dc7[7] = {-1,  0,-1, 0, 1, 0, 1};

    float st[2][4], sq2[2][4];
#pragma unroll
    for (int h = 0; h < 2; ++h)
#pragma unroll
        for (int r = 0; r < 4; ++r) { st[h][r] = 0.f; sq2[h][r] = 0.f; }

#pragma unroll
    for (int rr = 0; rr < 4; ++rr) {
        const int rl = wave * 4 + rr;
#pragma unroll
        for (int cg = 0; cg < 2; ++cg) {
            s16x8 B[7];
#pragma unroll
            for (int s = 0; s < 7; ++s)
                B[s] = *(const s16x8*)(&lds[((rl + 1 + dr7[s]) * 34 +
                                             (cg * 16 + n + 1 + dc7[s])) * 40 + q * 8]);
            f32x4 acc[2];
            acc[0] = (f32x4){0.f, 0.f, 0.f, 0.f};
            acc[1] = (f32x4){0.f, 0.f, 0.f, 0.f};
#pragma unroll
            for (int s = 0; s < 7; ++s)
#pragma unroll
                for (int h = 0; h < 2; ++h)
                    acc[h] = __builtin_amdgcn_mfma_f32_16x16x32_bf16(
                        A[s][h], B[s], acc[h], 0, 0, 0);
            const int i = i0 + rl;
            const int j = j0 + cg * 16 + n;
#pragma unroll
            for (int h = 0; h < 2; ++h)
#pragma unroll
                for (int r = 0; r < 4; ++r) {
                    const int co = h * 16 + q * 4 + r;
                    float v = acc[h][r];
                    y2[(((size_t)nb * 32 + co) * HY + i) * WY + j] = v;
                    st[h][r] += v; sq2[h][r] += v * v;
                }
        }
    }

    __syncthreads();
    float* scratch = (float*)lds;
#pragma unroll
    for (int h = 0; h < 2; ++h)
#pragma unroll
        for (int r = 0; r < 4; ++r) {
            float s = st[h][r], qv = sq2[h][r];
#pragma unroll
            for (int m = 1; m < 16; m <<= 1) {
                s  += __shfl_xor(s, m, 16);
                qv += __shfl_xor(qv, m, 16);
            }
            if (n == 0) {
                const int co = h * 16 + q * 4 + r;
                scratch[(wave * 32 + co) * 2]     = s;
                scratch[(wave * 32 + co) * 2 + 1] = qv;
            }
        }
    __syncthreads();
    if (t < 64) {
        const int co = t & 31, which = t >> 5;
        float s = scratch[(0 * 32 + co) * 2 + which] + scratch[(1 * 32 + co) * 2 + which]
                + scratch[(2 * 32 + co) * 2 + which] + scratch[(3 * 32 + co) * 2 + which];
        const int blk = blockIdx.y * 80 + blockIdx.x;            // 0..1279
        partialsB[(size_t)blk * 64 + which * 32 + co] = s;
    }
}

// ---------------------------------------------------------------------------
// params_final: y1 stats (partialsA cv=1) + y2 stats (partialsB) -> pf
// pf: [s1[32], t1[32], s2[32], t2[32]]
// ---------------------------------------------------------------------------
__global__ __launch_bounds__(256) void params_final_kernel(
    const float* __restrict__ partialsA, const float* __restrict__ partialsB,
    const float* __restrict__ g01, const float* __restrict__ b01,
    const float* __restrict__ g10, const float* __restrict__ b10,
    float* __restrict__ pf)
{
    __shared__ float red1[4][64], red2[4][64];
    __shared__ float tot1[64], tot2[64];
    const int t = threadIdx.x, c = t & 63, seg = t >> 6;
    float s1 = 0.f, s2 = 0.f;
    for (int b = seg; b < 640; b += 4)  s1 += partialsA[(size_t)(640 + b) * 64 + c];
    for (int b = seg; b < 1280; b += 4) s2 += partialsB[(size_t)b * 64 + c];
    red1[seg][c] = s1; red2[seg][c] = s2;
    __syncthreads();
    if (t < 64) {
        tot1[t] = red1[0][t] + red1[1][t] + red1[2][t] + red1[3][t];
        tot2[t] = red2[0][t] + red2[1][t] + red2[2][t] + red2[3][t];
    }
    __syncthreads();
    if (t < 32) {
        const float nf = (float)(NB * HY * WY);
        float m1 = tot1[t] / nf;
        float v1 = tot1[32 + t] / nf - m1 * m1;
        float r1 = rsqrtf(v1 + BN_EPS);
        float sc1 = g10[t] * r1;
        pf[t] = sc1;
        pf[32 + t] = b10[t] - m1 * sc1;
        float m2 = tot2[t] / nf;
        float v2 = tot2[32 + t] / nf - m2 * m2;
        float r2 = rsqrtf(v2 + BN_EPS);
        float sc2 = g01[t] * r2;
        pf[64 + t] = sc2;
        pf[96 + t] = b01[t] - m2 * sc2;
    }
}

// ---------------------------------------------------------------------------
// final: out = relu(bn(y2) + bn(y1)), float4
// ---------------------------------------------------------------------------
__global__ __launch_bounds__(256) void final_kernel(
    const float* __restrict__ y1, const float* __restrict__ y2,
    const float* __restrict__ pf, float* __restrict__ out)
{
    const int idx = blockIdx.x * 256 + threadIdx.x;
    const int c = (idx / 10240) & 31;
    const float s1 = pf[c], t1 = pf[32 + c];
    const float s2 = pf[64 + c], t2 = pf[96 + c];
    const float4 a = ((const float4*)y2)[idx];
    const float4 d = ((const float4*)y1)[idx];
    float4 r;
    r.x = fmaf(a.x, s2, t2) + fmaf(d.x, s1, t1);
    r.y = fmaf(a.y, s2, t2) + fmaf(d.y, s1, t1);
    r.z = fmaf(a.z, s2, t2) + fmaf(d.z, s1, t1);
    r.w = fmaf(a.w, s2, t2) + fmaf(d.w, s1, t1);
    r.x = r.x > 0.f ? r.x : 0.f;
    r.y = r.y > 0.f ? r.y : 0.f;
    r.z = r.z > 0.f ? r.z : 0.f;
    r.w = r.w > 0.f ? r.w : 0.f;
    ((float4*)out)[idx] = r;
}

// ---------------------------------------------------------------------------
extern "C" void kernel_launch(void* const* d_in, const int* in_sizes, int n_in,
                              void* d_out, int out_size, void* d_ws, size_t ws_size,
                              hipStream_t stream)
{
    (void)in_sizes; (void)n_in; (void)out_size; (void)ws_size;
    const float* x   = (const float*)d_in[0];
    const float* w00 = (const float*)d_in[1];
    const float* w01 = (const float*)d_in[2];
    const float* w10 = (const float*)d_in[3];
    const float* g00 = (const float*)d_in[4];
    const float* b00 = (const float*)d_in[5];
    const float* g01 = (const float*)d_in[6];
    const float* b01 = (const float*)d_in[7];
    const float* g10 = (const float*)d_in[8];
    const float* b10 = (const float*)d_in[9];
    float* out = (float*)d_out;

    // workspace (byte offsets, all 256B-aligned)
    char* ws = (char*)d_ws;
    const size_t NPLANE = (size_t)NB * COUT * HY * WY;       // 20,971,520
    float*          y1   = (float*)ws;                        ws += NPLANE * 4;
    float*          y2   = (float*)ws;                        ws += NPLANE * 4;
    __hip_bfloat16* y0h  = (__hip_bfloat16*)ws;               ws += NPLANE * 2;
    __hip_bfloat16* xt   = (__hip_bfloat16*)ws;               ws += (size_t)NB * CIN * HX * WX * 2;
    __hip_bfloat16* wAb  = (__hip_bfloat16*)ws;               ws += 2 * 16 * 32 * 64 * 2;
    __hip_bfloat16* wBb  = (__hip_bfloat16*)ws;               ws += 7 * 32 * 32 * 2 + 256;
    float*          pA   = (float*)ws;                        ws += 2 * 640 * 64 * 4;
    float*          pB   = (float*)ws;                        ws += 1280 * 64 * 4;
    float*          phs  = (float*)ws;                        ws += 256;
    float*          pf   = (float*)ws;

    prep_x<<<dim3(160, 16), dim3(256), 0, stream>>>(x, xt);
    prep_w<<<dim3(20), dim3(256), 0, stream>>>(w00, w01, w10, wAb, wBb);
    convA<<<dim3(40, 16, 2), dim3(256), 0, stream>>>(xt, wAb, y0h, y1, pA);
    params_h_kernel<<<dim3(1), dim3(256), 0, stream>>>(pA, g00, b00, phs);
    convB<<<dim3(80, 16), dim3(256), 0, stream>>>(y0h, wBb, phs, y2, pB);
    params_final_kernel<<<dim3(1), dim3(256), 0, stream>>>(pA, pB, g01, b01, g10, b10, pf);
    final_kernel<<<dim3((int)(NPLANE / 4 / 256)), dim3(256), 0, stream>>>(y1, y2, pf, out);
}

// Round 4
// 268.496 us; speedup vs baseline: 20.6160x; 1.5820x over previous
//
#include <hip/hip_runtime.h>
#include <hip/hip_bf16.h>

// BasicIcoS2SUpBlock — R4: bf16 MFMA implicit-GEMM + parallel stats reduce.
// R3 lesson: two single-block reduction kernels were latency-bound (115+60 us,
// VALUBusy 0.01%). Now tree-reduced (80-block stage1 -> tiny stage2).
// y1/y2 stored bf16 (stats still fp32 from accumulators) to halve HBM traffic.

#define CIN   64
#define COUT  32
#define HX    160
#define WX    64
#define HY    320
#define WY    128
#define NB    16
#define BN_EPS 1e-5f

typedef short s16x8 __attribute__((ext_vector_type(8)));
typedef float f32x4 __attribute__((ext_vector_type(4)));

// ---------------------------------------------------------------------------
// prep_x: x NCHW fp32 -> xt NHWC bf16 ([n][row160][col64][ci64], ci contig)
// ---------------------------------------------------------------------------
__global__ __launch_bounds__(256) void prep_x(const float* __restrict__ x,
                                              __hip_bfloat16* __restrict__ xt)
{
    __shared__ float tile[64][65];
    const int n  = blockIdx.y;
    const int p0 = blockIdx.x * 64;        // pixel tile (row-major px in-plane)
    const int t  = threadIdx.x;
#pragma unroll
    for (int e = 0; e < 16; ++e) {
        int k = e * 256 + t;
        int ci = k >> 6, p = k & 63;
        tile[ci][p] = x[(n * CIN + ci) * (HX * WX) + p0 + p];
    }
    __syncthreads();
#pragma unroll
    for (int e = 0; e < 16; ++e) {
        int k = e * 256 + t;
        int p = k >> 6, ci = k & 63;
        xt[((size_t)n * (HX * WX) + p0 + p) * 64 + ci] = __float2bfloat16(tile[ci][p]);
    }
}

// ---------------------------------------------------------------------------
// prep_w: effective phase weights (bf16).
// wAb: [cv(2)][slot(16)][co(32)][ci(64)]  slots = ph*4+s, dummy slots 7,11 = 0
// wBb: [tap(7)][co(32)][ci(32)]
// ---------------------------------------------------------------------------
__global__ __launch_bounds__(256) void prep_w(const float* __restrict__ w00,
                                              const float* __restrict__ w01,
                                              const float* __restrict__ w10,
                                              __hip_bfloat16* __restrict__ wAb,
                                              __hip_bfloat16* __restrict__ wBb)
{
    int t = blockIdx.x * 256 + threadIdx.x;
    if (t < 4096) {                       // convA weights
        int cv = t >> 11, u = t & 2047;
        int co = u >> 6, ci = u & 63;
        const float* w = (cv ? w10 : w00) + (co * 64 + ci) * 9;
        float a = w[0], b = w[1], c = w[3], d = w[4], e5 = w[5], f = w[7], g = w[8];
        float v[16];
        v[0] = a;             v[1] = b;           v[2] = c;       v[3] = d + e5 + f + g;
        v[4] = a + b;         v[5] = c + d + f;   v[6] = e5 + g;  v[7] = 0.f;
        v[8] = a + c;         v[9] = b + d + e5;  v[10] = f + g;  v[11] = 0.f;
        v[12] = a + b + c + d; v[13] = e5;        v[14] = f;      v[15] = g;
#pragma unroll
        for (int s = 0; s < 16; ++s)
            wAb[(((size_t)cv * 16 + s) * 32 + co) * 64 + ci] = __float2bfloat16(v[s]);
    } else if (t < 5120) {                // convB weights (hex taps of 3x3)
        int u = t - 4096;
        int co = u >> 5, ci = u & 31;
        const float* w = w01 + (co * 32 + ci) * 9;
        const int wi[7] = {0, 1, 3, 4, 5, 7, 8};
#pragma unroll
        for (int s = 0; s < 7; ++s)
            wBb[((size_t)s * 32 + co) * 32 + ci] = __float2bfloat16(w[wi[s]]);
    }
}

// ---------------------------------------------------------------------------
// convA: conv00 (cv=0 -> y0 NHWC bf16) / conv10 (cv=1 -> y1 NCHW bf16),
// phase-decomposed, MFMA 16x16x32 bf16. Block: 16x16 x-tile, 4 waves x 4 rows.
// LDS x-tile [18][18][ci 64 pad 72] bf16. Partial stats -> partialsA[cv][blk][64].
// ---------------------------------------------------------------------------
__global__ __launch_bounds__(256) void convA(
    const __hip_bfloat16* __restrict__ xt, const __hip_bfloat16* __restrict__ wAb,
    __hip_bfloat16* __restrict__ y0h, __hip_bfloat16* __restrict__ y1h,
    float* __restrict__ partialsA)
{
    __shared__ short lds[324 * 72];            // 18*18 chunks x 72 bf16 = 46656 B
    const int tb = blockIdx.x & 3, ta = blockIdx.x >> 2;
    const int nb = blockIdx.y, cv = blockIdx.z;
    const int t = threadIdx.x, wave = t >> 6, lane = t & 63;
    const int n = lane & 15, q = lane >> 4;
    const int a0 = ta * 16, b0 = tb * 16;

    // ---- stage x tile (rows wrap mod 160, cols zero-pad) ----
    for (int idx = t; idx < 2592; idx += 256) {       // 324 chunks * 8 lanes
        int chunk = idx >> 3, sub = idx & 7;
        int rl = chunk / 18, cl = chunk - rl * 18;
        int grow = a0 - 1 + rl;
        if (grow < 0) grow += HX; else if (grow >= HX) grow -= HX;
        int gcol = b0 - 1 + cl;
        uint4 v = make_uint4(0u, 0u, 0u, 0u);
        if ((unsigned)gcol < (unsigned)WX)
            v = *(const uint4*)(xt + (((size_t)nb * HX + grow) * WX + gcol) * 64 + sub * 8);
        *(uint4*)(&lds[chunk * 72 + sub * 8]) = v;
    }
    __syncthreads();

    // tap shifts per slot (ph*4+s); dummy slots point at (0,0), weight = 0
    const int dr16[16] = {-1,-1, 0, 0,  -1, 0, 0, 0,   0, 0, 1, 0,   0, 0, 1, 1};
    const int dc16[16] = {-1, 0,-1, 0,   0, 0, 1, 0,  -1, 0, 0, 0,   0, 1, 0, 1};

    float st[2][4], sq2[2][4];
#pragma unroll
    for (int h = 0; h < 2; ++h)
#pragma unroll
        for (int r = 0; r < 4; ++r) { st[h][r] = 0.f; sq2[h][r] = 0.f; }

#pragma unroll
    for (int ph = 0; ph < 4; ++ph) {
        const int pa = ph >> 1, pb = ph & 1;
        // A fragments: [tap][kc][h]
        s16x8 A[4][2][2];
#pragma unroll
        for (int ti = 0; ti < 4; ++ti)
#pragma unroll
            for (int kc = 0; kc < 2; ++kc)
#pragma unroll
                for (int h = 0; h < 2; ++h)
                    A[ti][kc][h] = *(const s16x8*)(wAb +
                        (((size_t)cv * 16 + ph * 4 + ti) * 32 + h * 16 + n) * 64 + kc * 32 + q * 8);
#pragma unroll
        for (int rr = 0; rr < 4; ++rr) {
            const int rl = wave * 4 + rr;
            s16x8 B[4][2];
#pragma unroll
            for (int ti = 0; ti < 4; ++ti) {
                const int off = ((rl + 1 + dr16[ph * 4 + ti]) * 18 + (n + 1 + dc16[ph * 4 + ti])) * 72;
#pragma unroll
                for (int kc = 0; kc < 2; ++kc)
                    B[ti][kc] = *(const s16x8*)(&lds[off + kc * 32 + q * 8]);
            }
            f32x4 acc[2];
            acc[0] = (f32x4){0.f, 0.f, 0.f, 0.f};
            acc[1] = (f32x4){0.f, 0.f, 0.f, 0.f};
#pragma unroll
            for (int ti = 0; ti < 4; ++ti)
#pragma unroll
                for (int kc = 0; kc < 2; ++kc)
#pragma unroll
                    for (int h = 0; h < 2; ++h)
                        acc[h] = __builtin_amdgcn_mfma_f32_16x16x32_bf16(
                            A[ti][kc][h], B[ti][kc], acc[h], 0, 0, 0);
            // store: out pixel (i, j), co = h*16 + q*4 + reg
            const int i = 2 * (a0 + rl) + pa;
            const int j = 2 * b0 + pb + 2 * n;
            if (cv == 0) {
                __hip_bfloat16* p = y0h + (((size_t)nb * HY + i) * WY + j) * 32;
#pragma unroll
                for (int h = 0; h < 2; ++h) {
                    __hip_bfloat162 lo = __float22bfloat162_rn(make_float2(acc[h][0], acc[h][1]));
                    __hip_bfloat162 hi = __float22bfloat162_rn(make_float2(acc[h][2], acc[h][3]));
                    __hip_bfloat162* pp = (__hip_bfloat162*)(p + h * 16 + q * 4);
                    pp[0] = lo; pp[1] = hi;
                }
            } else {
#pragma unroll
                for (int h = 0; h < 2; ++h)
#pragma unroll
                    for (int r = 0; r < 4; ++r) {
                        const int co = h * 16 + q * 4 + r;
                        y1h[(((size_t)nb * 32 + co) * HY + i) * WY + j] =
                            __float2bfloat16(acc[h][r]);
                    }
            }
#pragma unroll
            for (int h = 0; h < 2; ++h)
#pragma unroll
                for (int r = 0; r < 4; ++r) {
                    float v = acc[h][r];
                    st[h][r] += v; sq2[h][r] += v * v;
                }
        }
    }

    // ---- per-block stats reduction ----
    __syncthreads();
    float* scratch = (float*)lds;              // [wave][co][2]
#pragma unroll
    for (int h = 0; h < 2; ++h)
#pragma unroll
        for (int r = 0; r < 4; ++r) {
            float s = st[h][r], qv = sq2[h][r];
#pragma unroll
            for (int m = 1; m < 16; m <<= 1) {
                s  += __shfl_xor(s, m, 16);
                qv += __shfl_xor(qv, m, 16);
            }
            if (n == 0) {
                const int co = h * 16 + q * 4 + r;
                scratch[(wave * 32 + co) * 2]     = s;
                scratch[(wave * 32 + co) * 2 + 1] = qv;
            }
        }
    __syncthreads();
    if (t < 64) {
        const int co = t & 31, which = t >> 5;
        float s = scratch[(0 * 32 + co) * 2 + which] + scratch[(1 * 32 + co) * 2 + which]
                + scratch[(2 * 32 + co) * 2 + which] + scratch[(3 * 32 + co) * 2 + which];
        const int blk = blockIdx.y * 40 + blockIdx.x;          // 0..639
        partialsA[((size_t)cv * 640 + blk) * 64 + which * 32 + co] = s;
    }
}

// ---------------------------------------------------------------------------
// reduce16: block b reduces src[b*16 .. b*16+15][64] -> dst[b][64]
// ---------------------------------------------------------------------------
__global__ __launch_bounds__(256) void reduce16(const float* __restrict__ src,
                                                float* __restrict__ dst)
{
    __shared__ float red[4][64];
    const int t = threadIdx.x, c = t & 63, seg = t >> 6;
    const float* s = src + (size_t)blockIdx.x * 16 * 64;
    float acc = 0.f;
#pragma unroll
    for (int r = 0; r < 4; ++r) acc += s[(seg + r * 4) * 64 + c];
    red[seg][c] = acc;
    __syncthreads();
    if (t < 64)
        dst[(size_t)blockIdx.x * 64 + t] = red[0][t] + red[1][t] + red[2][t] + red[3][t];
}

// ---------------------------------------------------------------------------
// params_h: redA rows 0..39 (= conv00 partials) -> BN scale/shift for h.
// phs: [s32, t32]
// ---------------------------------------------------------------------------
__global__ void params_h_kernel(const float* __restrict__ redA,
                                const float* __restrict__ g00,
                                const float* __restrict__ b00,
                                float* __restrict__ phs)
{
    __shared__ float tot[64];
    const int t = threadIdx.x;
    float s = 0.f;
    for (int b = 0; b < 40; ++b) s += redA[b * 64 + t];
    tot[t] = s;
    __syncthreads();
    if (t < 32) {
        const float nf = (float)(NB * HY * WY);
        float mean = tot[t] / nf;
        float var  = tot[32 + t] / nf - mean * mean;
        float sc = g00[t] * rsqrtf(var + BN_EPS);
        phs[t] = sc;
        phs[32 + t] = b00[t] - mean * sc;
    }
}

// ---------------------------------------------------------------------------
// convB: conv01 on h = relu(bn(y0)) (BN+ReLU fused into bf16 staging).
// Block: 16x32 out-tile, LDS [18][34][ci 32 pad 40]. MFMA 16x16x32, K=32.
// ---------------------------------------------------------------------------
__global__ __launch_bounds__(256) void convB(
    const __hip_bfloat16* __restrict__ y0h, const __hip_bfloat16* __restrict__ wBb,
    const float* __restrict__ phs, __hip_bfloat16* __restrict__ y2h,
    float* __restrict__ partialsB)
{
    __shared__ short lds[612 * 40];            // 18*34 chunks x 40 = 48960 B
    const int tj = blockIdx.x & 3, ti = blockIdx.x >> 2;
    const int nb = blockIdx.y;
    const int t = threadIdx.x, wave = t >> 6, lane = t & 63;
    const int n = lane & 15, q = lane >> 4;
    const int i0 = ti * 16, j0 = tj * 32;

    // BN params for this lane's 8 staged channels
    const int cis = (t & 3) * 8;
    float sv[8], tv[8];
#pragma unroll
    for (int e = 0; e < 8; ++e) { sv[e] = phs[cis + e]; tv[e] = phs[32 + cis + e]; }

    // ---- stage h tile ----
    for (int idx = t; idx < 2448; idx += 256) {      // 612 chunks * 4 lanes
        int chunk = idx >> 2, sub = idx & 3;         // sub == t&3 (256 % 4 == 0)
        int rl = chunk / 34, cl = chunk - rl * 34;
        int grow = i0 - 1 + rl;
        if (grow < 0) grow += HY; else if (grow >= HY) grow -= HY;
        int gcol = j0 - 1 + cl;
        uint4 w = make_uint4(0u, 0u, 0u, 0u);
        if ((unsigned)gcol < (unsigned)WY) {
            uint4 v = *(const uint4*)(y0h + (((size_t)nb * HY + grow) * WY + gcol) * 32 + sub * 8);
            unsigned* vi = (unsigned*)&v;
            unsigned* wi = (unsigned*)&w;
#pragma unroll
            for (int k = 0; k < 4; ++k) {
                unsigned u = vi[k];
                float f0 = __uint_as_float(u << 16);
                float f1 = __uint_as_float(u & 0xffff0000u);
                f0 = fmaxf(fmaf(f0, sv[2 * k], tv[2 * k]), 0.f);
                f1 = fmaxf(fmaf(f1, sv[2 * k + 1], tv[2 * k + 1]), 0.f);
                union { __hip_bfloat162 b2; unsigned u32; } cvt;
                cvt.b2 = __float22bfloat162_rn(make_float2(f0, f1));
                wi[k] = cvt.u32;
            }
        }
        *(uint4*)(&lds[chunk * 40 + sub * 8]) = w;
    }
    __syncthreads();

    // A fragments [tap][h]
    s16x8 A[7][2];
#pragma unroll
    for (int s = 0; s < 7; ++s)
#pragma unroll
        for (int h = 0; h < 2; ++h)
            A[s][h] = *(const s16x8*)(wBb + ((size_t)s * 32 + h * 16 + n) * 32 + q * 8);

    const int dr7[7] = {-1, -1, 0, 0, 0, 1, 1};
    const int dc7[7] = {-1,  0,-1, 0, 1, 0, 1};

    float st[2][4], sq2[2][4];
#pragma unroll
    for (int h = 0; h < 2; ++h)
#pragma unroll
        for (int r = 0; r < 4; ++r) { st[h][r] = 0.f; sq2[h][r] = 0.f; }

#pragma unroll
    for (int rr = 0; rr < 4; ++rr) {
        const int rl = wave * 4 + rr;
#pragma unroll
        for (int cg = 0; cg < 2; ++cg) {
            s16x8 B[7];
#pragma unroll
            for (int s = 0; s < 7; ++s)
                B[s] = *(const s16x8*)(&lds[((rl + 1 + dr7[s]) * 34 +
                                             (cg * 16 + n + 1 + dc7[s])) * 40 + q * 8]);
            f32x4 acc[2];
            acc[0] = (f32x4){0.f, 0.f, 0.f, 0.f};
            acc[1] = (f32x4){0.f, 0.f, 0.f, 0.f};
#pragma unroll
            for (int s = 0; s < 7; ++s)
#pragma unroll
                for (int h = 0; h < 2; ++h)
                    acc[h] = __builtin_amdgcn_mfma_f32_16x16x32_bf16(
                        A[s][h], B[s], acc[h], 0, 0, 0);
            const int i = i0 + rl;
            const int j = j0 + cg * 16 + n;
#pragma unroll
            for (int h = 0; h < 2; ++h)
#pragma unroll
                for (int r = 0; r < 4; ++r) {
                    const int co = h * 16 + q * 4 + r;
                    float v = acc[h][r];
                    y2h[(((size_t)nb * 32 + co) * HY + i) * WY + j] = __float2bfloat16(v);
                    st[h][r] += v; sq2[h][r] += v * v;
                }
        }
    }

    __syncthreads();
    float* scratch = (float*)lds;
#pragma unroll
    for (int h = 0; h < 2; ++h)
#pragma unroll
        for (int r = 0; r < 4; ++r) {
            float s = st[h][r], qv = sq2[h][r];
#pragma unroll
            for (int m = 1; m < 16; m <<= 1) {
                s  += __shfl_xor(s, m, 16);
                qv += __shfl_xor(qv, m, 16);
            }
            if (n == 0) {
                const int co = h * 16 + q * 4 + r;
                scratch[(wave * 32 + co) * 2]     = s;
                scratch[(wave * 32 + co) * 2 + 1] = qv;
            }
        }
    __syncthreads();
    if (t < 64) {
        const int co = t & 31, which = t >> 5;
        float s = scratch[(0 * 32 + co) * 2 + which] + scratch[(1 * 32 + co) * 2 + which]
                + scratch[(2 * 32 + co) * 2 + which] + scratch[(3 * 32 + co) * 2 + which];
        const int blk = blockIdx.y * 80 + blockIdx.x;            // 0..1279
        partialsB[(size_t)blk * 64 + which * 32 + co] = s;
    }
}

// ---------------------------------------------------------------------------
// params_final: redA rows 40..79 (conv10) + redB rows 0..79 (conv01) -> pf
// pf: [s1[32], t1[32], s2[32], t2[32]]
// ---------------------------------------------------------------------------
__global__ void params_final_kernel(const float* __restrict__ redA,
                                    const float* __restrict__ redB,
                                    const float* __restrict__ g01,
                                    const float* __restrict__ b01,
                                    const float* __restrict__ g10,
                                    const float* __restrict__ b10,
                                    float* __restrict__ pf)
{
    __shared__ float tot1[64], tot2[64];
    const int t = threadIdx.x;
    float s1 = 0.f, s2 = 0.f;
    for (int b = 0; b < 40; ++b) s1 += redA[(40 + b) * 64 + t];
    for (int b = 0; b < 80; ++b) s2 += redB[b * 64 + t];
    tot1[t] = s1; tot2[t] = s2;
    __syncthreads();
    if (t < 32) {
        const float nf = (float)(NB * HY * WY);
        float m1 = tot1[t] / nf;
        float v1 = tot1[32 + t] / nf - m1 * m1;
        float sc1 = g10[t] * rsqrtf(v1 + BN_EPS);
        pf[t] = sc1;
        pf[32 + t] = b10[t] - m1 * sc1;
        float m2 = tot2[t] / nf;
        float v2 = tot2[32 + t] / nf - m2 * m2;
        float sc2 = g01[t] * rsqrtf(v2 + BN_EPS);
        pf[64 + t] = sc2;
        pf[96 + t] = b01[t] - m2 * sc2;
    }
}

// ---------------------------------------------------------------------------
// final: out = relu(bn(y2) + bn(y1)), 8 bf16 elems/thread -> fp32 out
// ---------------------------------------------------------------------------
__global__ __launch_bounds__(256) void final_kernel(
    const __hip_bfloat16* __restrict__ y1h, const __hip_bfloat16* __restrict__ y2h,
    const float* __restrict__ pf, float* __restrict__ out)
{
    const size_t e0 = ((size_t)blockIdx.x * 256 + threadIdx.x) * 8;
    const int c = (int)((e0 / (HY * WY)) & 31);
    const float s1 = pf[c], t1 = pf[32 + c];
    const float s2 = pf[64 + c], t2 = pf[96 + c];
    uint4 a = *(const uint4*)(y2h + e0);
    uint4 d = *(const uint4*)(y1h + e0);
    const unsigned* ai = (const unsigned*)&a;
    const unsigned* di = (const unsigned*)&d;
    float r[8];
#pragma unroll
    for (int k = 0; k < 4; ++k) {
        float a0 = __uint_as_float(ai[k] << 16);
        float a1 = __uint_as_float(ai[k] & 0xffff0000u);
        float d0 = __uint_as_float(di[k] << 16);
        float d1 = __uint_as_float(di[k] & 0xffff0000u);
        float r0 = fmaf(a0, s2, t2) + fmaf(d0, s1, t1);
        float r1 = fmaf(a1, s2, t2) + fmaf(d1, s1, t1);
        r[2 * k]     = r0 > 0.f ? r0 : 0.f;
        r[2 * k + 1] = r1 > 0.f ? r1 : 0.f;
    }
    float4* o = (float4*)(out + e0);
    o[0] = make_float4(r[0], r[1], r[2], r[3]);
    o[1] = make_float4(r[4], r[5], r[6], r[7]);
}

// ---------------------------------------------------------------------------
extern "C" void kernel_launch(void* const* d_in, const int* in_sizes, int n_in,
                              void* d_out, int out_size, void* d_ws, size_t ws_size,
                              hipStream_t stream)
{
    (void)in_sizes; (void)n_in; (void)out_size; (void)ws_size;
    const float* x   = (const float*)d_in[0];
    const float* w00 = (const float*)d_in[1];
    const float* w01 = (const float*)d_in[2];
    const float* w10 = (const float*)d_in[3];
    const float* g00 = (const float*)d_in[4];
    const float* b00 = (const float*)d_in[5];
    const float* g01 = (const float*)d_in[6];
    const float* b01 = (const float*)d_in[7];
    const float* g10 = (const float*)d_in[8];
    const float* b10 = (const float*)d_in[9];
    float* out = (float*)d_out;

    // workspace (byte offsets, all 256B-aligned)
    char* ws = (char*)d_ws;
    const size_t NPLANE = (size_t)NB * COUT * HY * WY;       // 20,971,520
    __hip_bfloat16* y1h  = (__hip_bfloat16*)ws;               ws += NPLANE * 2;
    __hip_bfloat16* y2h  = (__hip_bfloat16*)ws;               ws += NPLANE * 2;
    __hip_bfloat16* y0h  = (__hip_bfloat16*)ws;               ws += NPLANE * 2;
    __hip_bfloat16* xt   = (__hip_bfloat16*)ws;               ws += (size_t)NB * CIN * HX * WX * 2;
    __hip_bfloat16* wAb  = (__hip_bfloat16*)ws;               ws += 2 * 16 * 32 * 64 * 2;
    __hip_bfloat16* wBb  = (__hip_bfloat16*)ws;               ws += 7 * 32 * 32 * 2 + 256;
    float*          pA   = (float*)ws;                        ws += 2 * 640 * 64 * 4;
    float*          pB   = (float*)ws;                        ws += 1280 * 64 * 4;
    float*          redA = (float*)ws;                        ws += 80 * 64 * 4;
    float*          redB = (float*)ws;                        ws += 80 * 64 * 4;
    float*          phs  = (float*)ws;                        ws += 256;
    float*          pf   = (float*)ws;

    prep_x<<<dim3(160, 16), dim3(256), 0, stream>>>(x, xt);
    prep_w<<<dim3(20), dim3(256), 0, stream>>>(w00, w01, w10, wAb, wBb);
    convA<<<dim3(40, 16, 2), dim3(256), 0, stream>>>(xt, wAb, y0h, y1h, pA);
    reduce16<<<dim3(80), dim3(256), 0, stream>>>(pA, redA);
    params_h_kernel<<<dim3(1), dim3(64), 0, stream>>>(redA, g00, b00, phs);
    convB<<<dim3(80, 16), dim3(256), 0, stream>>>(y0h, wBb, phs, y2h, pB);
    reduce16<<<dim3(80), dim3(256), 0, stream>>>(pB, redB);
    params_final_kernel<<<dim3(1), dim3(64), 0, stream>>>(redA, redB, g01, b01, g10, b10, pf);
    final_kernel<<<dim3((int)(NPLANE / 8 / 256)), dim3(256), 0, stream>>>(y1h, y2h, pf, out);
}